// Round 11
// baseline (235.943 us; speedup 1.0000x reference)
//
#include <hip/hip_runtime.h>

#define NHID   512
#define NCLS   250
#define CHUNK  200
#define NTOK   2048
#define NOUT   450
#define MAXTOK 32
#define NTHR   256

#define CLS_UNITS 1024                      // 128 M-tiles x 8 ntile-pairs
#define WRD_UNITS (NCLS * 7)                // 250 x 7 ntile-pairs (13 tiles)
#define NUNITS    (CLS_UNITS + WRD_UNITS)   // 2774
#define NBLK      ((NUNITS + 3) / 4)        // 694 blocks x 4 waves

typedef __attribute__((ext_vector_type(8))) short bf16x8;
typedef __attribute__((ext_vector_type(4))) float f32x4;

__global__ void scatter_kernel(const int* __restrict__ cls_idx,
                               int* __restrict__ cnt, int* __restrict__ list) {
    int i = blockIdx.x * blockDim.x + threadIdx.x;
    if (i < NTOK) {
        int c = cls_idx[i];
        int p = atomicAdd(&cnt[c], 1);
        if (p < MAXTOK) list[c * MAXTOK + p] = i;
    }
}

// pack hi bf16 of (e1,e0) into one uint: (hi16(a)<<16)|hi16(b)
__device__ __forceinline__ unsigned hpack(unsigned a, unsigned b) {
    return __builtin_amdgcn_perm(a, b, 0x07060302u);
}

// fp32x8 -> hi/lo split bf16x8 (truncate hi; lo = truncate(exact residual))
__device__ __forceinline__ void cvt8(float4 va, float4 vb, bf16x8& h, bf16x8& l) {
    unsigned u0 = __float_as_uint(va.x), u1 = __float_as_uint(va.y);
    unsigned u2 = __float_as_uint(va.z), u3 = __float_as_uint(va.w);
    unsigned u4 = __float_as_uint(vb.x), u5 = __float_as_uint(vb.y);
    unsigned u6 = __float_as_uint(vb.z), u7 = __float_as_uint(vb.w);
    union { unsigned w[4]; bf16x8 v; } H, L;
    H.w[0] = hpack(u1, u0); H.w[1] = hpack(u3, u2);
    H.w[2] = hpack(u5, u4); H.w[3] = hpack(u7, u6);
    float r0 = va.x - __uint_as_float(u0 & 0xffff0000u);
    float r1 = va.y - __uint_as_float(u1 & 0xffff0000u);
    float r2 = va.z - __uint_as_float(u2 & 0xffff0000u);
    float r3 = va.w - __uint_as_float(u3 & 0xffff0000u);
    float r4 = vb.x - __uint_as_float(u4 & 0xffff0000u);
    float r5 = vb.y - __uint_as_float(u5 & 0xffff0000u);
    float r6 = vb.z - __uint_as_float(u6 & 0xffff0000u);
    float r7 = vb.w - __uint_as_float(u7 & 0xffff0000u);
    L.w[0] = hpack(__float_as_uint(r1), __float_as_uint(r0));
    L.w[1] = hpack(__float_as_uint(r3), __float_as_uint(r2));
    L.w[2] = hpack(__float_as_uint(r5), __float_as_uint(r4));
    L.w[3] = hpack(__float_as_uint(r7), __float_as_uint(r6));
    h = H.v; l = L.v;
}

__global__ __launch_bounds__(NTHR, 2)
void cbd_mfma(const float* __restrict__ x,  const float* __restrict__ Wc,
              const float* __restrict__ bc, const float* __restrict__ Ww,
              const float* __restrict__ bw, const int* __restrict__ cnt_ws,
              const int* __restrict__ list_ws, float* __restrict__ out)
{
    const int unit = blockIdx.x * 4 + (threadIdx.x >> 6);
    if (unit >= NUNITS) return;
    const int l = threadIdx.x & 63;
    const int n = l & 15;        // lane's row slot (A: token; B/D: W row)
    const int q = l >> 4;        // k-quad

    const bool is_cls = unit < CLS_UNITS;
    int c = 0, ntp, m0 = 0, mlim, count = 0;
    if (is_cls) {
        int mtile = unit >> 3;
        ntp  = unit & 7;
        m0   = mtile * 16;
        mlim = m0 + 16;
    } else {
        int v = unit - CLS_UNITS;
        c   = v / 7;
        ntp = v % 7;
        count = cnt_ws[c];
        if (count <= 0) return;
        if (count > MAXTOK) count = MAXTOK;
        mlim = count;
    }

    // ---- B side: this unit's two N-tiles ----
    const int r0 = (2 * ntp) * 16 + n;
    const int r1 = r0 + 16;
    bool rv0, rv1; int col0, col1; float bias0, bias1;
    const float *bpt0, *bpt1;
    if (is_cls) {
        rv0 = r0 < NCLS; rv1 = r1 < NCLS;
        int rc0 = rv0 ? r0 : NCLS - 1, rc1 = rv1 ? r1 : NCLS - 1;
        bpt0 = Wc + (size_t)rc0 * NHID + q * 8;
        bpt1 = Wc + (size_t)rc1 * NHID + q * 8;
        bias0 = bc[rc0]; bias1 = bc[rc1];
        col0 = rc0; col1 = rc1;
    } else {
        rv0 = r0 < CHUNK; rv1 = r1 < CHUNK;
        int rc0 = rv0 ? r0 : CHUNK - 1, rc1 = rv1 ? r1 : CHUNK - 1;
        bpt0 = Ww + ((size_t)c * CHUNK + rc0) * NHID + q * 8;
        bpt1 = Ww + ((size_t)c * CHUNK + rc1) * NHID + q * 8;
        bias0 = bw[c * CHUNK + rc0]; bias1 = bw[c * CHUNK + rc1];
        col0 = NCLS + rc0; col1 = NCLS + rc1;
    }

    for (int mbase = m0; mbase < mlim; mbase += 16) {
        // ---- A side: lane's token row ----
        int tokA, tokS[4]; bool sv[4];
        if (is_cls) {
            tokA = mbase + n;
            #pragma unroll
            for (int i = 0; i < 4; ++i) { tokS[i] = mbase + q * 4 + i; sv[i] = true; }
        } else {
            int mi = mbase + n;
            tokA = list_ws[c * MAXTOK + (mi < count ? mi : count - 1)];
            #pragma unroll
            for (int i = 0; i < 4; ++i) {
                int m = mbase + q * 4 + i;
                sv[i]   = m < count;
                tokS[i] = list_ws[c * MAXTOK + (sv[i] ? m : count - 1)];
            }
        }
        const float* ap = x + (size_t)tokA * NHID + q * 8;

        f32x4 acc0 = {0.f, 0.f, 0.f, 0.f};
        f32x4 acc1 = {0.f, 0.f, 0.f, 0.f};

        // ---- k-loop: 16 steps, explicit 3-slot register ring ----
        float4 Pa0,Pa1,Pb0,Pb1,Pc0,Pc1;
        float4 Qa0,Qa1,Qb0,Qb1,Qc0,Qc1;
        float4 Ra0,Ra1,Rb0,Rb1,Rc0,Rc1;

#define LDR(S, A0,A1,B0,B1,C0,C1) {                                          \
        int _s = (S) < 16 ? (S) : 15;                                        \
        const float* _a = ap   + _s * 32;                                    \
        const float* _b = bpt0 + _s * 32;                                    \
        const float* _c = bpt1 + _s * 32;                                    \
        A0 = *(const float4*)_a; A1 = *(const float4*)(_a + 4);              \
        B0 = *(const float4*)_b; B1 = *(const float4*)(_b + 4);              \
        C0 = *(const float4*)_c; C1 = *(const float4*)(_c + 4); }

#define CMPR(A0,A1,B0,B1,C0,C1) {                                            \
        bf16x8 ah, al, bh, bl;                                               \
        cvt8(A0, A1, ah, al);                                                \
        cvt8(B0, B1, bh, bl);                                                \
        acc0 = __builtin_amdgcn_mfma_f32_16x16x32_bf16(ah, bh, acc0, 0,0,0); \
        acc0 = __builtin_amdgcn_mfma_f32_16x16x32_bf16(al, bh, acc0, 0,0,0); \
        acc0 = __builtin_amdgcn_mfma_f32_16x16x32_bf16(ah, bl, acc0, 0,0,0); \
        cvt8(C0, C1, bh, bl);                                                \
        acc1 = __builtin_amdgcn_mfma_f32_16x16x32_bf16(ah, bh, acc1, 0,0,0); \
        acc1 = __builtin_amdgcn_mfma_f32_16x16x32_bf16(al, bh, acc1, 0,0,0); \
        acc1 = __builtin_amdgcn_mfma_f32_16x16x32_bf16(ah, bl, acc1, 0,0,0); }

        LDR(0, Pa0,Pa1,Pb0,Pb1,Pc0,Pc1);
        LDR(1, Qa0,Qa1,Qb0,Qb1,Qc0,Qc1);
        LDR(2, Ra0,Ra1,Rb0,Rb1,Rc0,Rc1);
        for (int s = 0; s < 15; s += 3) {
            CMPR(Pa0,Pa1,Pb0,Pb1,Pc0,Pc1);  LDR(s + 3, Pa0,Pa1,Pb0,Pb1,Pc0,Pc1);
            CMPR(Qa0,Qa1,Qb0,Qb1,Qc0,Qc1);  LDR(s + 4, Qa0,Qa1,Qb0,Qb1,Qc0,Qc1);
            CMPR(Ra0,Ra1,Rb0,Rb1,Rc0,Rc1);  LDR(s + 5, Ra0,Ra1,Rb0,Rb1,Rc0,Rc1);
        }
        CMPR(Pa0,Pa1,Pb0,Pb1,Pc0,Pc1);      // step 15
#undef LDR
#undef CMPR

        // ---- epilogue: D col = lane&15 (W row), D row m = q*4 + reg ----
        #pragma unroll
        for (int i = 0; i < 4; ++i) {
            if (sv[i]) {
                size_t ro = (size_t)tokS[i] * NOUT;
                if (rv0) out[ro + col0] = acc0[i] + bias0;
                if (rv1) out[ro + col1] = acc1[i] + bias1;
            }
        }
    }
}

extern "C" void kernel_launch(void* const* d_in, const int* in_sizes, int n_in,
                              void* d_out, int out_size, void* d_ws, size_t ws_size,
                              hipStream_t stream) {
    const float* x   = (const float*)d_in[0];
    const float* Wc  = (const float*)d_in[1];
    const float* bc  = (const float*)d_in[2];
    const float* Ww  = (const float*)d_in[3];
    const float* bw  = (const float*)d_in[4];
    const int*   cls = (const int*)d_in[5];
    float* out = (float*)d_out;

    int* cnt  = (int*)d_ws;            // 256 counters (250 used)
    int* list = cnt + 256;             // 250*32 token lists

    hipMemsetAsync(cnt, 0, 256 * sizeof(int), stream);
    hipLaunchKernelGGL(scatter_kernel, dim3((NTOK + 255) / 256), dim3(256),
                       0, stream, cls, cnt, list);
    hipLaunchKernelGGL(cbd_mfma, dim3(NBLK), dim3(NTHR), 0, stream,
                       x, Wc, bc, Ww, bw, cnt, list, out);
}

// Round 12
// 190.639 us; speedup vs baseline: 1.2376x; 1.2376x over previous
//
#include <hip/hip_runtime.h>

#define NHID   512
#define NCLS   250
#define CHUNK  200
#define NTOK   2048
#define NOUT   450
#define NTHR   128
#define NBLK   258
#define MAXTOK 32

typedef __attribute__((ext_vector_type(8))) short bf16x8;
typedef __attribute__((ext_vector_type(4))) float f32x4;

#define MFMA(a, b, c) __builtin_amdgcn_mfma_f32_16x16x32_bf16((a), (b), (c), 0, 0, 0)

__device__ __forceinline__ unsigned hpack(unsigned a, unsigned b) {
    return __builtin_amdgcn_perm(a, b, 0x07060302u);
}

// fp32x8 -> hi/lo split bf16x8 (truncate hi; lo = truncate(exact residual))
__device__ __forceinline__ void cvt8(float4 va, float4 vb, bf16x8& h, bf16x8& l) {
    unsigned u0 = __float_as_uint(va.x), u1 = __float_as_uint(va.y);
    unsigned u2 = __float_as_uint(va.z), u3 = __float_as_uint(va.w);
    unsigned u4 = __float_as_uint(vb.x), u5 = __float_as_uint(vb.y);
    unsigned u6 = __float_as_uint(vb.z), u7 = __float_as_uint(vb.w);
    union { unsigned w[4]; bf16x8 v; } H, L;
    H.w[0] = hpack(u1, u0); H.w[1] = hpack(u3, u2);
    H.w[2] = hpack(u5, u4); H.w[3] = hpack(u7, u6);
    float r0 = va.x - __uint_as_float(u0 & 0xffff0000u);
    float r1 = va.y - __uint_as_float(u1 & 0xffff0000u);
    float r2 = va.z - __uint_as_float(u2 & 0xffff0000u);
    float r3 = va.w - __uint_as_float(u3 & 0xffff0000u);
    float r4 = vb.x - __uint_as_float(u4 & 0xffff0000u);
    float r5 = vb.y - __uint_as_float(u5 & 0xffff0000u);
    float r6 = vb.z - __uint_as_float(u6 & 0xffff0000u);
    float r7 = vb.w - __uint_as_float(u7 & 0xffff0000u);
    L.w[0] = hpack(__float_as_uint(r1), __float_as_uint(r0));
    L.w[1] = hpack(__float_as_uint(r3), __float_as_uint(r2));
    L.w[2] = hpack(__float_as_uint(r5), __float_as_uint(r4));
    L.w[3] = hpack(__float_as_uint(r7), __float_as_uint(r6));
    h = H.v; l = L.v;
}

// async 16B/lane global->LDS (wave-uniform LDS base + lane*16)
__device__ __forceinline__ void async16(const float* g, float* lds_base) {
    __builtin_amdgcn_global_load_lds(
        (const __attribute__((address_space(1))) unsigned*)g,
        (__attribute__((address_space(3))) unsigned*)lds_base, 16, 0, 0);
}

__device__ __forceinline__ void lds_fence_wave() {
    __builtin_amdgcn_wave_barrier();
    asm volatile("s_waitcnt lgkmcnt(0)" ::: "memory");
    __builtin_amdgcn_wave_barrier();
}

__global__ __launch_bounds__(NTHR, 1)
void cbd_fused(const float* __restrict__ x,  const float* __restrict__ Wc,
               const float* __restrict__ bc, const float* __restrict__ Ww,
               const float* __restrict__ bw, const int* __restrict__ cls_idx,
               float* __restrict__ out)
{
    __shared__ short Afrag[2][16 * 64 * 8];   // 32 KB: [hi/lo][(s*64+lane)*8]
    __shared__ float Bbuf[2][16 * 256];       // 32 KB: [buf][row*256 + k]

    const int bid  = blockIdx.x;
    const int tid  = threadIdx.x;
    const int wid  = tid >> 6;
    const int lane = tid & 63;
    const int n    = lane & 15;   // fragment row slot
    const int q    = lane >> 4;   // k-quad

    if (wid == 1) {
        // ================= wave 1: p_class (direct-global, L2-hot Wc) ========
        if (bid < 256) {
            const int mt = bid >> 1, hn = bid & 1;
            const float* ap = x + (size_t)(mt * 16 + n) * NHID + q * 8;
            #pragma unroll
            for (int g4 = 0; g4 < 2; ++g4) {
                const float* bp[4]; float bias[4]; int col[4]; bool rv[4];
                #pragma unroll
                for (int k = 0; k < 4; ++k) {
                    int r = (hn * 8 + g4 * 4 + k) * 16 + n;
                    rv[k] = r < NCLS;
                    int rc = rv[k] ? r : NCLS - 1;
                    bp[k]   = Wc + (size_t)rc * NHID + q * 8;
                    bias[k] = bc[rc];
                    col[k]  = rc;
                }
                f32x4 acc[4] = {{0,0,0,0},{0,0,0,0},{0,0,0,0},{0,0,0,0}};
                #pragma unroll 2
                for (int s = 0; s < 16; ++s) {
                    float4 a0 = *(const float4*)(ap + s * 32);
                    float4 a1 = *(const float4*)(ap + s * 32 + 4);
                    bf16x8 ah, al; cvt8(a0, a1, ah, al);
                    #pragma unroll
                    for (int k = 0; k < 4; ++k) {
                        float4 b0 = *(const float4*)(bp[k] + s * 32);
                        float4 b1 = *(const float4*)(bp[k] + s * 32 + 4);
                        bf16x8 bh, bl; cvt8(b0, b1, bh, bl);
                        acc[k] = MFMA(ah, bh, acc[k]);
                        acc[k] = MFMA(al, bh, acc[k]);
                        acc[k] = MFMA(ah, bl, acc[k]);
                    }
                }
                #pragma unroll
                for (int k = 0; k < 4; ++k)
                    if (rv[k]) {
                        #pragma unroll
                        for (int i = 0; i < 4; ++i)
                            out[(size_t)(mt * 16 + q * 4 + i) * NOUT + col[k]]
                                = acc[k][i] + bias[k];
                    }
            }
        }
        return;
    }

    // ================= wave 0: p_words (async-DMA pipelined) =================
    // load all of cls_idx into registers (coalesced int4)
    int myvals[32];
    #pragma unroll
    for (int it = 0; it < 8; ++it) {
        int4 v = *(const int4*)&cls_idx[it * 256 + lane * 4];
        myvals[it*4+0] = v.x; myvals[it*4+1] = v.y;
        myvals[it*4+2] = v.z; myvals[it*4+3] = v.w;
    }

    int c, slotbase;
    const float* wsrc;
    bool issued01 = false;
    if (bid < NCLS) {
        c = bid; slotbase = 0;
        wsrc = Ww + (size_t)c * CHUNK * NHID;
        // early issue: half-panels 0 (p0,k-lo) and 1 (p0,k-hi)
        #pragma unroll
        for (int r = 0; r < 16; ++r)
            async16(wsrc + (size_t)r * NHID + lane * 4, &Bbuf[0][r * 256]);
        #pragma unroll
        for (int r = 0; r < 16; ++r)
            async16(wsrc + (size_t)r * NHID + 256 + lane * 4, &Bbuf[1][r * 256]);
        issued01 = true;
    } else {
        // overflow block: LDS histogram -> k-th class with count>16
        int* hist = (int*)&Bbuf[0][0];
        for (int i = lane; i < 256; i += 64) hist[i] = 0;
        lds_fence_wave();
        #pragma unroll
        for (int j = 0; j < 32; ++j) atomicAdd(&hist[myvals[j]], 1);
        lds_fence_wave();
        int kk = bid - NCLS, found = -1, runbase = 0;
        #pragma unroll
        for (int ch = 0; ch < 4; ++ch) {
            int hv = hist[ch * 64 + lane];
            unsigned long long m = __ballot(hv > 16);
            int c2 = (int)__popcll(m);
            if (found < 0 && kk < runbase + c2) {
                unsigned long long mm = m;
                for (int t = 0; t < 8; ++t) if (t < kk - runbase) mm &= mm - 1;
                found = ch * 64 + (__ffsll((long long)mm) - 1);
            }
            runbase += c2;
        }
        if (found < 0) return;
        c = found; slotbase = 16;
        wsrc = Ww + (size_t)c * CHUNK * NHID;
    }

    // ---- token list via ballots (no atomics), scratch in Afrag space ----
    int* toktmp = (int*)&Afrag[0][0];
    int cnt = 0;
    #pragma unroll
    for (int j = 0; j < 32; ++j) {
        int idx  = (j >> 2) * 256 + lane * 4 + (j & 3);
        bool hit = (myvals[j] == c);
        unsigned long long m = __ballot(hit);
        if (hit) {
            int pos = cnt + (int)__popcll(m & ((1ull << lane) - 1ull));
            if (pos < MAXTOK) toktmp[pos] = idx;
        }
        cnt += (int)__popcll(m);
    }
    const int cntc = cnt < MAXTOK ? cnt : MAXTOK;
    if (slotbase >= cntc || cntc == 0) {   // nothing to do: drain & exit
        if (issued01) asm volatile("s_waitcnt vmcnt(0)" ::: "memory");
        return;
    }
    lds_fence_wave();
    int idx_slot = slotbase + n;
    int mytokr   = toktmp[idx_slot < cntc ? idx_slot : 0];
    lds_fence_wave();

    if (!issued01) {   // overflow: issue first two half-panels now
        #pragma unroll
        for (int r = 0; r < 16; ++r)
            async16(wsrc + (size_t)r * NHID + lane * 4, &Bbuf[0][r * 256]);
        #pragma unroll
        for (int r = 0; r < 16; ++r)
            async16(wsrc + (size_t)r * NHID + 256 + lane * 4, &Bbuf[1][r * 256]);
    }

    // tokens this lane stores (D rows m = q*4+i), hoisted to full-exec
    int tkS[4]; bool msk[4];
    #pragma unroll
    for (int i = 0; i < 4; ++i) {
        int ml = q * 4 + i;
        tkS[i] = __shfl(mytokr, ml);
        msk[i] = (slotbase + ml) < cntc;
    }

    // ---- stage A fragments (split-bf16, lane-linear = conflict-free) ----
    {
        int tk = __shfl(mytokr, n);
        #pragma unroll
        for (int it = 0; it < 16; ++it) {
            const float* xp = x + (size_t)tk * NHID + it * 32 + q * 8;
            float4 va = *(const float4*)xp, vb = *(const float4*)(xp + 4);
            bf16x8 hh, ll; cvt8(va, vb, hh, ll);
            int u = it * 64 + lane;
            *(bf16x8*)&Afrag[0][u * 8] = hh;
            *(bf16x8*)&Afrag[1][u * 8] = ll;
        }
    }
    lds_fence_wave();

    // ---- half-panel pipeline: hp = 2*p + h, 26 half-panels ----
    f32x4 acc = {0.f, 0.f, 0.f, 0.f};
    for (int hp = 0; hp < 26; ++hp) {
        const int p = hp >> 1, h = hp & 1, buf = hp & 1;
        asm volatile("s_waitcnt vmcnt(0)" ::: "memory");
        __builtin_amdgcn_wave_barrier();

        if (h == 0) { acc[0] = 0.f; acc[1] = 0.f; acc[2] = 0.f; acc[3] = 0.f; }
        #pragma unroll
        for (int ss = 0; ss < 8; ++ss) {
            const int sg = h * 8 + ss;
            bf16x8 ah = *(const bf16x8*)&Afrag[0][(sg * 64 + lane) * 8];
            bf16x8 al = *(const bf16x8*)&Afrag[1][(sg * 64 + lane) * 8];
            const float* bq = &Bbuf[buf][n * 256 + ss * 32 + q * 8];
            float4 b0 = *(const float4*)bq;
            float4 b1 = *(const float4*)(bq + 4);
            bf16x8 bh, bl; cvt8(b0, b1, bh, bl);
            acc = MFMA(ah, bh, acc);
            acc = MFMA(al, bh, acc);
            acc = MFMA(ah, bl, acc);
        }

        if (h == 1) {
            int r = p * 16 + n;
            if (r < CHUNK) {
                float bias = bw[c * CHUNK + r];
                #pragma unroll
                for (int i = 0; i < 4; ++i)
                    if (msk[i])
                        out[(size_t)tkS[i] * NOUT + NCLS + r] = acc[i] + bias;
            }
        }

        // issue half-panel hp+2 into this buffer
        if (hp + 2 < 26) {
            const int p2 = (hp + 2) >> 1, h2 = (hp + 2) & 1;
            const int nrow = (p2 == 12) ? 8 : 16;
            const float* base = wsrc + (size_t)(p2 * 16) * NHID + h2 * 256 + lane * 4;
            for (int r = 0; r < nrow; ++r)
                async16(base + (size_t)r * NHID, &Bbuf[buf][r * 256]);
        }
    }
}

extern "C" void kernel_launch(void* const* d_in, const int* in_sizes, int n_in,
                              void* d_out, int out_size, void* d_ws, size_t ws_size,
                              hipStream_t stream) {
    const float* x   = (const float*)d_in[0];
    const float* Wc  = (const float*)d_in[1];
    const float* bc  = (const float*)d_in[2];
    const float* Ww  = (const float*)d_in[3];
    const float* bw  = (const float*)d_in[4];
    const int*   cls = (const int*)d_in[5];
    float* out = (float*)d_out;
    hipLaunchKernelGGL(cbd_fused, dim3(NBLK), dim3(NTHR), 0, stream,
                       x, Wc, bc, Ww, bw, cls, out);
}

// Round 13
// 179.918 us; speedup vs baseline: 1.3114x; 1.0596x over previous
//
#include <hip/hip_runtime.h>

#define NHID   512
#define NCLS   250
#define CHUNK  200
#define NTOK   2048
#define NOUT   450
#define NTHR   128
#define NBLK   258
#define MAXTOK 32
#define BPAD   260   // B row stride in floats: 1040 B (16B-aligned, breaks bank alias)

typedef __attribute__((ext_vector_type(8))) short bf16x8;
typedef __attribute__((ext_vector_type(4))) float f32x4;

#define MFMA(a, b, c) __builtin_amdgcn_mfma_f32_16x16x32_bf16((a), (b), (c), 0, 0, 0)

__device__ __forceinline__ unsigned hpack(unsigned a, unsigned b) {
    return __builtin_amdgcn_perm(a, b, 0x07060302u);
}

// fp32x8 -> hi/lo split bf16x8 (truncate hi; lo = truncate(exact residual))
__device__ __forceinline__ void cvt8(float4 va, float4 vb, bf16x8& h, bf16x8& l) {
    unsigned u0 = __float_as_uint(va.x), u1 = __float_as_uint(va.y);
    unsigned u2 = __float_as_uint(va.z), u3 = __float_as_uint(va.w);
    unsigned u4 = __float_as_uint(vb.x), u5 = __float_as_uint(vb.y);
    unsigned u6 = __float_as_uint(vb.z), u7 = __float_as_uint(vb.w);
    union { unsigned w[4]; bf16x8 v; } H, L;
    H.w[0] = hpack(u1, u0); H.w[1] = hpack(u3, u2);
    H.w[2] = hpack(u5, u4); H.w[3] = hpack(u7, u6);
    float r0 = va.x - __uint_as_float(u0 & 0xffff0000u);
    float r1 = va.y - __uint_as_float(u1 & 0xffff0000u);
    float r2 = va.z - __uint_as_float(u2 & 0xffff0000u);
    float r3 = va.w - __uint_as_float(u3 & 0xffff0000u);
    float r4 = vb.x - __uint_as_float(u4 & 0xffff0000u);
    float r5 = vb.y - __uint_as_float(u5 & 0xffff0000u);
    float r6 = vb.z - __uint_as_float(u6 & 0xffff0000u);
    float r7 = vb.w - __uint_as_float(u7 & 0xffff0000u);
    L.w[0] = hpack(__float_as_uint(r1), __float_as_uint(r0));
    L.w[1] = hpack(__float_as_uint(r3), __float_as_uint(r2));
    L.w[2] = hpack(__float_as_uint(r5), __float_as_uint(r4));
    L.w[3] = hpack(__float_as_uint(r7), __float_as_uint(r6));
    h = H.v; l = L.v;
}

// async 16B/lane global->LDS (wave-uniform LDS base; HW adds lane*16)
__device__ __forceinline__ void async16(const float* g, float* lds_base) {
    __builtin_amdgcn_global_load_lds(
        (const __attribute__((address_space(1))) unsigned*)g,
        (__attribute__((address_space(3))) unsigned*)lds_base, 16, 0, 0);
}

__device__ __forceinline__ void lds_fence_wave() {
    __builtin_amdgcn_wave_barrier();
    asm volatile("s_waitcnt lgkmcnt(0)" ::: "memory");
    __builtin_amdgcn_wave_barrier();
}

__global__ __launch_bounds__(NTHR, 1)
void cbd_fused(const float* __restrict__ x,  const float* __restrict__ Wc,
               const float* __restrict__ bc, const float* __restrict__ Ww,
               const float* __restrict__ bw, const int* __restrict__ cls_idx,
               float* __restrict__ out)
{
    __shared__ short Afrag[2][16 * 64 * 8];   // 32 KB split-bf16 A fragments
    __shared__ float Bbuf[2][16 * BPAD];      // 2 x 16.6 KB DMA ring
    __shared__ float bias_s[208];

    const int bid  = blockIdx.x;
    const int tid  = threadIdx.x;
    const int wid  = tid >> 6;
    const int lane = tid & 63;
    const int n    = lane & 15;   // fragment row slot
    const int q    = lane >> 4;   // k-quad

    if (wid == 1) {
        // ================= wave 1: p_class (direct-global, L2-hot Wc) ========
        if (bid < 256) {
            const int mt = bid >> 1, hn = bid & 1;
            const float* ap = x + (size_t)(mt * 16 + n) * NHID + q * 8;
            #pragma unroll
            for (int g4 = 0; g4 < 2; ++g4) {
                const float* bp[4]; float bias[4]; int col[4]; bool rv[4];
                #pragma unroll
                for (int k = 0; k < 4; ++k) {
                    int r = (hn * 8 + g4 * 4 + k) * 16 + n;
                    rv[k] = r < NCLS;
                    int rc = rv[k] ? r : NCLS - 1;
                    bp[k]   = Wc + (size_t)rc * NHID + q * 8;
                    bias[k] = bc[rc];
                    col[k]  = rc;
                }
                f32x4 acc[4] = {{0,0,0,0},{0,0,0,0},{0,0,0,0},{0,0,0,0}};
                #pragma unroll 2
                for (int s = 0; s < 16; ++s) {
                    float4 a0 = *(const float4*)(ap + s * 32);
                    float4 a1 = *(const float4*)(ap + s * 32 + 4);
                    bf16x8 ah, al; cvt8(a0, a1, ah, al);
                    #pragma unroll
                    for (int k = 0; k < 4; ++k) {
                        float4 b0 = *(const float4*)(bp[k] + s * 32);
                        float4 b1 = *(const float4*)(bp[k] + s * 32 + 4);
                        bf16x8 bh, bl; cvt8(b0, b1, bh, bl);
                        acc[k] = MFMA(ah, bh, acc[k]);
                        acc[k] = MFMA(al, bh, acc[k]);
                        acc[k] = MFMA(ah, bl, acc[k]);
                    }
                }
                #pragma unroll
                for (int k = 0; k < 4; ++k)
                    if (rv[k]) {
                        #pragma unroll
                        for (int i = 0; i < 4; ++i)
                            out[(size_t)(mt * 16 + q * 4 + i) * NOUT + col[k]]
                                = acc[k][i] + bias[k];
                    }
            }
        }
        return;
    }

    // ================= wave 0: p_words (async-DMA pipelined) =================
    int myvals[32];
    #pragma unroll
    for (int it = 0; it < 8; ++it) {
        int4 v = *(const int4*)&cls_idx[it * 256 + lane * 4];
        myvals[it*4+0] = v.x; myvals[it*4+1] = v.y;
        myvals[it*4+2] = v.z; myvals[it*4+3] = v.w;
    }

    // ---- resolve this block's class ----
    int c, slotbase;
    if (bid < NCLS) {
        c = bid; slotbase = 0;
    } else {
        int* hist = (int*)&Afrag[1][0];
        for (int i = lane; i < 256; i += 64) hist[i] = 0;
        lds_fence_wave();
        #pragma unroll
        for (int j = 0; j < 32; ++j) atomicAdd(&hist[myvals[j]], 1);
        lds_fence_wave();
        int kk = bid - NCLS, found = -1, runbase = 0;
        #pragma unroll
        for (int ch = 0; ch < 4; ++ch) {
            int hv = hist[ch * 64 + lane];
            unsigned long long m = __ballot(hv > 16);
            int c2 = (int)__popcll(m);
            if (found < 0 && kk < runbase + c2) {
                unsigned long long mm = m;
                for (int t = 0; t < 8; ++t) if (t < kk - runbase) mm &= mm - 1;
                found = ch * 64 + (__ffsll((long long)mm) - 1);
            }
            runbase += c2;
        }
        lds_fence_wave();   // hist reads done before Afrag reused
        if (found < 0) return;
        c = found; slotbase = 16;
    }
    const float* wsrc = Ww + (size_t)c * CHUNK * NHID;

    // ---- issue half-panels 0,1 FIRST (earliest possible DMA start) ----
    #pragma unroll
    for (int r = 0; r < 16; ++r)
        async16(wsrc + (size_t)r * NHID + lane * 4, &Bbuf[0][r * BPAD]);
    #pragma unroll
    for (int r = 0; r < 16; ++r)
        async16(wsrc + (size_t)r * NHID + 256 + lane * 4, &Bbuf[1][r * BPAD]);

    // ---- token list via ballots (no atomics) ----
    int* toktmp = (int*)&Afrag[0][0];
    int cnt = 0;
    #pragma unroll
    for (int j = 0; j < 32; ++j) {
        int idx  = (j >> 2) * 256 + lane * 4 + (j & 3);
        bool hit = (myvals[j] == c);
        unsigned long long m = __ballot(hit);
        if (hit) {
            int pos = cnt + (int)__popcll(m & ((1ull << lane) - 1ull));
            if (pos < MAXTOK) toktmp[pos] = idx;
        }
        cnt += (int)__popcll(m);
    }
    const int cntc = cnt < MAXTOK ? cnt : MAXTOK;
    if (slotbase >= cntc) {   // nothing to do: drain issued DMA & exit
        asm volatile("s_waitcnt vmcnt(0)" ::: "memory");
        return;
    }
    lds_fence_wave();
    int idx_slot = slotbase + n;
    int mytokr   = toktmp[idx_slot < cntc ? idx_slot : 0];
    lds_fence_wave();

    // tokens this lane stores (D rows m = q*4+i)
    int tkS[4]; bool msk[4];
    #pragma unroll
    for (int i = 0; i < 4; ++i) {
        int ml = q * 4 + i;
        tkS[i] = __shfl(mytokr, ml);
        msk[i] = (slotbase + ml) < cntc;
    }

    // ---- stage biases into LDS (no global loads inside the k-loop!) ----
    for (int i = lane; i < CHUNK; i += 64) bias_s[i] = bw[c * CHUNK + i];

    // ---- stage A fragments (split-bf16, lane-linear) ----
    {
        int tk = __shfl(mytokr, n);
        #pragma unroll
        for (int it = 0; it < 16; ++it) {
            const float* xp = x + (size_t)tk * NHID + it * 32 + q * 8;
            float4 va = *(const float4*)xp, vb = *(const float4*)(xp + 4);
            bf16x8 hh, ll; cvt8(va, vb, hh, ll);
            int u = it * 64 + lane;
            *(bf16x8*)&Afrag[0][u * 8] = hh;
            *(bf16x8*)&Afrag[1][u * 8] = ll;
        }
    }
    lds_fence_wave();

    // ---- half-panel pipeline: hp = 2*p + h; fine-grained vmcnt pacing ----
    f32x4 acc = {0.f, 0.f, 0.f, 0.f};
    for (int hp = 0; hp < 26; ++hp) {
        // in-order retirement: panel hp's 16 items are older than the <=16
        // newer (panel hp+1); vmcnt(16) guarantees hp's LDS writes landed.
        if (hp < 25) asm volatile("s_waitcnt vmcnt(16)" ::: "memory");
        else         asm volatile("s_waitcnt vmcnt(0)"  ::: "memory");

        const int p = hp >> 1, h = hp & 1, buf = hp & 1;
        if (h == 0) { acc[0] = 0.f; acc[1] = 0.f; acc[2] = 0.f; acc[3] = 0.f; }
        #pragma unroll
        for (int ss = 0; ss < 8; ++ss) {
            const int sg = h * 8 + ss;
            bf16x8 ah = *(const bf16x8*)&Afrag[0][(sg * 64 + lane) * 8];
            bf16x8 al = *(const bf16x8*)&Afrag[1][(sg * 64 + lane) * 8];
            const float* bq = &Bbuf[buf][n * BPAD + ss * 32 + q * 8];
            float4 b0 = *(const float4*)bq;
            float4 b1 = *(const float4*)(bq + 4);
            bf16x8 bh, bl; cvt8(b0, b1, bh, bl);
            acc = MFMA(ah, bh, acc);
            acc = MFMA(al, bh, acc);
            acc = MFMA(ah, bl, acc);
        }

        if (h == 1) {
            int r = p * 16 + n;
            if (r < CHUNK) {
                float bias = bias_s[r];            // LDS read — no vmcnt impact
                #pragma unroll
                for (int i = 0; i < 4; ++i)
                    if (msk[i])
                        out[(size_t)tkS[i] * NOUT + NCLS + r] = acc[i] + bias;
            }
        }

        // refill this buffer with half-panel hp+2 (reads of buf finished above)
        if (hp + 2 < 26) {
            const int p2 = (hp + 2) >> 1, h2 = (hp + 2) & 1;
            const int koff = h2 * 256;
            #pragma unroll
            for (int r = 0; r < 16; ++r) {
                int rr = p2 * 16 + r; if (rr > CHUNK - 1) rr = CHUNK - 1;
                async16(wsrc + (size_t)rr * NHID + koff + lane * 4,
                        &Bbuf[buf][r * BPAD]);
            }
        }
    }
}

extern "C" void kernel_launch(void* const* d_in, const int* in_sizes, int n_in,
                              void* d_out, int out_size, void* d_ws, size_t ws_size,
                              hipStream_t stream) {
    const float* x   = (const float*)d_in[0];
    const float* Wc  = (const float*)d_in[1];
    const float* bc  = (const float*)d_in[2];
    const float* Ww  = (const float*)d_in[3];
    const float* bw  = (const float*)d_in[4];
    const int*   cls = (const int*)d_in[5];
    float* out = (float*)d_out;
    hipLaunchKernelGGL(cbd_fused, dim3(NBLK), dim3(NTHR), 0, stream,
                       x, Wc, bc, Ww, bw, cls, out);
}